// Round 6
// baseline (764.369 us; speedup 1.0000x reference)
//
#include <hip/hip_runtime.h>
#include <hip/hip_bf16.h>

#define LNUM 4
#define BB 16
#define SS 16
#define KVC 2048
#define HH 6
#define DD 128
#define HIDN 768
#define FFN 2048
#define NCH 17           // 16 cache chunks of 128 keys + 1 "new keys" chunk
#define ATT_SCALE 0.08838834764831845f
#define VT_PAD 136
#define OSH_PAD 132

typedef unsigned short u16;
typedef short s16x8 __attribute__((ext_vector_type(8)));
typedef unsigned short u16x4 __attribute__((ext_vector_type(4)));
typedef float f32x4 __attribute__((ext_vector_type(4)));

__device__ __forceinline__ short f2bfs(float f) {
    __hip_bfloat16 h = __float2bfloat16(f);   // RNE; pairs into v_cvt_pk_bf16_f32
    return *reinterpret_cast<short*>(&h);
}

// ---------- rope table: tab[s][d] = (sin, cos) for pos=KVC+s ---------------------------
__global__ __launch_bounds__(64) void rope_tab_k(float2* __restrict__ tab) {
    int i = blockIdx.x * 64 + threadIdx.x;   // 1024
    int s = i >> 6, d = i & 63;
    float ts = powf(10000.f, (float)d * (1.f / 64.f));
    float rad = (float)(KVC + s) / ts;
    tab[i] = make_float2(sinf(rad), cosf(rad));
}

// ---------- ALL weight transposes in one launch ---------------------------------------
// in f32 [K][N] -> out bf16 [N][K]. LDS stride 65 u16 (read step 4 mod 32 dw, no conflict)
__global__ __launch_bounds__(256) void wtrans_all_k(
    const float* __restrict__ Wq, const float* __restrict__ Wk, const float* __restrict__ Wv,
    const float* __restrict__ Wo, const float* __restrict__ Wg, const float* __restrict__ Wu,
    const float* __restrict__ Wd,
    u16* __restrict__ WqT, u16* __restrict__ WkT, u16* __restrict__ WvT, u16* __restrict__ WoT,
    u16* __restrict__ WgT, u16* __restrict__ WuT, u16* __restrict__ WdT) {
    int idx = blockIdx.x, z = blockIdx.y;
    const float* in; u16* out; int K, N, nx, tt;
    if (idx < 432)      { tt = idx % 144; K = 768;  N = 768;  nx = 12;
                          int w = idx / 144;
                          in = (w==0)?Wq:(w==1)?Wk:Wv; out = (w==0)?WqT:(w==1)?WkT:WvT; }
    else if (idx < 576) { tt = idx - 432; K = 768;  N = 768;  nx = 12; in = Wo; out = WoT; }
    else if (idx < 1344){ tt = (idx - 576) % 384; K = 768; N = 2048; nx = 32;
                          in = (idx < 960) ? Wg : Wu; out = (idx < 960) ? WgT : WuT; }
    else                { tt = idx - 1344; K = 2048; N = 768; nx = 12; in = Wd; out = WdT; }
    int n0 = (tt % nx) * 64, k0 = (tt / nx) * 64;
    in  += (size_t)z * K * N;
    out += (size_t)z * K * N;
    __shared__ u16 T[64][65];
    int t = threadIdx.x;
#pragma unroll
    for (int i = 0; i < 16; ++i) {
        int f = i * 256 + t;
        int k = f >> 6, n = f & 63;
        T[k][n] = (u16)f2bfs(in[(size_t)(k0 + k) * N + n0 + n]);
    }
    __syncthreads();
#pragma unroll
    for (int i = 0; i < 2; ++i) {
        int f = i * 256 + t;
        int n = f >> 3, kg = f & 7;
        s16x8 v;
#pragma unroll
        for (int j = 0; j < 8; ++j) v[j] = (short)T[kg * 8 + j][n];
        *(s16x8*)(out + (size_t)(n0 + n) * K + k0 + kg * 8) = v;
    }
}

// ---------- RMSNorm: one wave per token row; OUTBF: write bf16 else f32 ---------------
template<int OUTBF>
__global__ __launch_bounds__(64) void rmsnorm_k(const float* __restrict__ x,
                                                const float* __restrict__ w,
                                                void* __restrict__ yv) {
    int row = blockIdx.x, lane = threadIdx.x;
    const float* xp = x + (size_t)row * HIDN + lane * 12;
    float4 a = *(const float4*)xp;
    float4 b = *(const float4*)(xp + 4);
    float4 c = *(const float4*)(xp + 8);
    float s = a.x*a.x + a.y*a.y + a.z*a.z + a.w*a.w
            + b.x*b.x + b.y*b.y + b.z*b.z + b.w*b.w
            + c.x*c.x + c.y*c.y + c.z*c.z + c.w*c.w;
    for (int m = 1; m < 64; m <<= 1) s += __shfl_xor(s, m);
    float rq = rsqrtf(s * (1.f / 768.f) + 1e-6f);
    const float* wp = w + lane * 12;
    float v[12];
#pragma unroll
    for (int i = 0; i < 4; ++i) { v[i]   = (&a.x)[i] * rq * wp[i]; }
#pragma unroll
    for (int i = 0; i < 4; ++i) { v[4+i] = (&b.x)[i] * rq * wp[4+i]; }
#pragma unroll
    for (int i = 0; i < 4; ++i) { v[8+i] = (&c.x)[i] * rq * wp[8+i]; }
    if (OUTBF) {
        u16* y = (u16*)yv + (size_t)row * HIDN + lane * 12;
#pragma unroll
        for (int i = 0; i < 3; ++i) {
            u16x4 o;
#pragma unroll
            for (int j = 0; j < 4; ++j) o[j] = (u16)f2bfs(v[i * 4 + j]);
            *(u16x4*)(y + i * 4) = o;
        }
    } else {
        float* y = (float*)yv + (size_t)row * HIDN + lane * 12;
#pragma unroll
        for (int i = 0; i < 3; ++i) {
            float4 o; o.x = v[i*4]; o.y = v[i*4+1]; o.z = v[i*4+2]; o.w = v[i*4+3];
            *(float4*)(y + i * 4) = o;
        }
    }
}

// ---------- fused QKV GEMM + bias + rope(table) -> qr/kr/vr bf16 (b,h,s,d) ------------
__global__ __launch_bounds__(64) void qkv_k(const u16* __restrict__ hn,
                                            const u16* __restrict__ WqT, const u16* __restrict__ WkT,
                                            const u16* __restrict__ WvT,
                                            const float* __restrict__ bq, const float* __restrict__ bk,
                                            const float* __restrict__ bv,
                                            const float2* __restrict__ tab,
                                            u16* __restrict__ qr, u16* __restrict__ kr,
                                            u16* __restrict__ vr) {
    int x = blockIdx.x, b = blockIdx.y;
    int kind = x / HH, h = x % HH;
    const u16* Wt = (kind == 0) ? WqT : (kind == 1) ? WkT : WvT;
    const float* bias = (kind == 0) ? bq : (kind == 1) ? bk : bv;
    u16* outp = (kind == 0) ? qr : (kind == 1) ? kr : vr;
    int lane = threadIdx.x, r = lane & 15, qg = lane >> 4;
    f32x4 acc[8];
#pragma unroll
    for (int nt = 0; nt < 8; ++nt) acc[nt] = (f32x4){0.f, 0.f, 0.f, 0.f};
#pragma unroll 2
    for (int k0 = 0; k0 < HIDN; k0 += 32) {
        s16x8 a = *(const s16x8*)(hn + (size_t)(b * 16 + r) * HIDN + k0 + qg * 8);
#pragma unroll
        for (int nt = 0; nt < 8; ++nt) {
            s16x8 bw = *(const s16x8*)(Wt + (size_t)(h * DD + nt * 16 + r) * HIDN + k0 + qg * 8);
            acc[nt] = __builtin_amdgcn_mfma_f32_16x16x32_bf16(a, bw, acc[nt], 0, 0, 0);
        }
    }
    int bh = b * HH + h;
    if (kind < 2) {
#pragma unroll
        for (int nt = 0; nt < 4; ++nt) {
            int d1 = nt * 16 + r, d2 = d1 + 64;
            float b1 = bias[h * DD + d1], b2 = bias[h * DD + d2];
#pragma unroll
            for (int v = 0; v < 4; ++v) {
                int s = qg * 4 + v;
                float2 sc = tab[s * 64 + d1];
                float x1 = acc[nt][v] + b1;
                float x2 = acc[nt + 4][v] + b2;
                outp[(size_t)(bh * 16 + s) * DD + d1] = (u16)f2bfs(x1 * sc.y - x2 * sc.x);
                outp[(size_t)(bh * 16 + s) * DD + d2] = (u16)f2bfs(x2 * sc.y + x1 * sc.x);
            }
        }
    } else {
#pragma unroll
        for (int nt = 0; nt < 8; ++nt) {
            int d = nt * 16 + r;
            float bb = bias[h * DD + d];
#pragma unroll
            for (int v = 0; v < 4; ++v)
                outp[(size_t)(bh * 16 + qg * 4 + v) * DD + d] = (u16)f2bfs(acc[nt][v] + bb);
        }
    }
}

// ---------- attention partials: WG = 4 waves, 128 keys/WG, V staged transposed in LDS -
__global__ __launch_bounds__(256) void attn_part_k(
    const u16* __restrict__ qr, const u16* __restrict__ kr, const u16* __restrict__ vr,
    const float* __restrict__ kc, const float* __restrict__ vc,
    float* __restrict__ part_o, float* __restrict__ part_ml) {
    int bh = blockIdx.x, ch = blockIdx.y;
    int tid = threadIdx.x, wid = tid >> 6, lane = tid & 63, r = lane & 15, qg = lane >> 4;
    bool isnew = (ch == NCH - 1);
    bool active = !isnew || (wid == 0);
    __shared__ __align__(16) char smem[128 * VT_PAD * 2];  // Vt, later reused as Osh
    u16* Vt = (u16*)smem;
    float* Osh = (float*)smem;
    __shared__ __align__(16) u16 Plds[4][512];
    __shared__ float mlsh[4][32];

    const float* vbase_wg = vc + ((size_t)bh * KVC + ch * 128) * DD;
    const u16* vrn = vr + (size_t)bh * SS * DD;

    if (!isnew) {
#pragma unroll
        for (int i = 0; i < 8; ++i) {
            int flat = i * 256 + tid;
            int c4 = flat & 31, rp = flat >> 5;
            const float* p0 = vbase_wg + (size_t)(2 * rp) * DD + c4 * 4;
            float4 a = *(const float4*)p0;
            float4 b = *(const float4*)(p0 + DD);
#pragma unroll
            for (int c = 0; c < 4; ++c) {
                unsigned lo = (unsigned)(u16)f2bfs((&a.x)[c]);
                unsigned hi = (unsigned)(u16)f2bfs((&b.x)[c]);
                *(unsigned*)(Vt + (size_t)(c4 * 4 + c) * VT_PAD + 2 * rp) = lo | (hi << 16);
            }
        }
    } else {
#pragma unroll
        for (int i = 0; i < 16; ++i) {
            int flat = i * 256 + tid;
            int key = flat >> 7, d = flat & 127;
            u16 v = (key < SS) ? vrn[(size_t)key * DD + d] : (u16)0;
            Vt[(size_t)d * VT_PAD + key] = v;
        }
    }
    __syncthreads();

    float mrow[4] = {-1e30f, -1e30f, -1e30f, -1e30f};
    float lrow[4] = {0.f, 0.f, 0.f, 0.f};
    f32x4 oacc[8];
#pragma unroll
    for (int nt = 0; nt < 8; ++nt) oacc[nt] = (f32x4){0.f, 0.f, 0.f, 0.f};

    if (active) {
        s16x8 aq[4];
#pragma unroll
        for (int kk = 0; kk < 4; ++kk)
            aq[kk] = *(const s16x8*)(qr + (size_t)(bh * 16 + r) * DD + kk * 32 + qg * 8);
        const float* kbase = kc + ((size_t)bh * KVC + ch * 128 + wid * 32) * DD;
        const u16* krn = kr + (size_t)bh * SS * DD;

        f32x4 st[2];
        st[0] = (f32x4){0.f,0.f,0.f,0.f};
        st[1] = (f32x4){0.f,0.f,0.f,0.f};
#pragma unroll
        for (int t = 0; t < 2; ++t) {
            if (isnew && t == 1) continue;
#pragma unroll
            for (int kk = 0; kk < 4; ++kk) {
                s16x8 bk;
                if (isnew) {
                    bk = *(const s16x8*)(krn + (size_t)(t * 16 + r) * DD + kk * 32 + qg * 8);
                } else {
                    const float* p = kbase + (size_t)(t * 16 + r) * DD + kk * 32 + qg * 8;
                    float4 xx = *(const float4*)p;
                    float4 yy = *(const float4*)(p + 4);
                    bk[0]=f2bfs(xx.x); bk[1]=f2bfs(xx.y); bk[2]=f2bfs(xx.z); bk[3]=f2bfs(xx.w);
                    bk[4]=f2bfs(yy.x); bk[5]=f2bfs(yy.y); bk[6]=f2bfs(yy.z); bk[7]=f2bfs(yy.w);
                }
                st[t] = __builtin_amdgcn_mfma_f32_16x16x32_bf16(aq[kk], bk, st[t], 0, 0, 0);
            }
        }
#pragma unroll
        for (int t = 0; t < 2; ++t)
#pragma unroll
            for (int v = 0; v < 4; ++v) st[t][v] *= ATT_SCALE;
        if (isnew) {
#pragma unroll
            for (int v = 0; v < 4; ++v) {
                if (r > qg * 4 + v) st[0][v] = -1e9f;
                st[1][v] = -1e9f;
            }
        }
#pragma unroll
        for (int v = 0; v < 4; ++v) {
            float xm = fmaxf(st[0][v], st[1][v]);
            for (int msk = 1; msk < 16; msk <<= 1) xm = fmaxf(xm, __shfl_xor(xm, msk));
            mrow[v] = xm;
        }
#pragma unroll
        for (int t = 0; t < 2; ++t)
#pragma unroll
            for (int v = 0; v < 4; ++v) st[t][v] = __expf(st[t][v] - mrow[v]);
#pragma unroll
        for (int v = 0; v < 4; ++v) {
            float ss = st[0][v] + st[1][v];
            for (int msk = 1; msk < 16; msk <<= 1) ss += __shfl_xor(ss, msk);
            lrow[v] = ss;
        }
#pragma unroll
        for (int t = 0; t < 2; ++t)
#pragma unroll
            for (int v = 0; v < 4; ++v)
                Plds[wid][(qg * 4 + v) * 32 + t * 16 + r] = (u16)f2bfs(st[t][v]);
        s16x8 ap = *(const s16x8*)(&Plds[wid][r * 32 + qg * 8]);
#pragma unroll
        for (int nt = 0; nt < 8; ++nt) {
            s16x8 bv = *(const s16x8*)(Vt + (size_t)(nt * 16 + r) * VT_PAD + wid * 32 + qg * 8);
            oacc[nt] = __builtin_amdgcn_mfma_f32_16x16x32_bf16(ap, bv, oacc[nt], 0, 0, 0);
        }
    }
    __syncthreads();
#pragma unroll
    for (int nt = 0; nt < 8; ++nt)
#pragma unroll
        for (int v = 0; v < 4; ++v)
            Osh[(size_t)(wid * 16 + qg * 4 + v) * OSH_PAD + nt * 16 + r] = oacc[nt][v];
    if (r == 0) {
#pragma unroll
        for (int v = 0; v < 4; ++v) {
            mlsh[wid][qg * 4 + v] = mrow[v];
            mlsh[wid][16 + qg * 4 + v] = lrow[v];
        }
    }
    __syncthreads();
    int q = tid >> 4, dg = tid & 15;
    float M = -1e30f;
#pragma unroll
    for (int w = 0; w < 4; ++w) M = fmaxf(M, mlsh[w][q]);
    float L = 0.f, wgt[4];
#pragma unroll
    for (int w = 0; w < 4; ++w) {
        wgt[w] = __expf(mlsh[w][q] - M);
        L += mlsh[w][16 + q] * wgt[w];
    }
    float o[8];
#pragma unroll
    for (int j = 0; j < 8; ++j) o[j] = 0.f;
#pragma unroll
    for (int w = 0; w < 4; ++w) {
        const float* op = Osh + (size_t)(w * 16 + q) * OSH_PAD + dg * 8;
        float4 a = *(const float4*)op;
        float4 b = *(const float4*)(op + 4);
        o[0]+=wgt[w]*a.x; o[1]+=wgt[w]*a.y; o[2]+=wgt[w]*a.z; o[3]+=wgt[w]*a.w;
        o[4]+=wgt[w]*b.x; o[5]+=wgt[w]*b.y; o[6]+=wgt[w]*b.z; o[7]+=wgt[w]*b.w;
    }
    float* po = part_o + ((size_t)bh * NCH + ch) * (SS * DD) + q * DD + dg * 8;
    float4 o0; o0.x=o[0]; o0.y=o[1]; o0.z=o[2]; o0.w=o[3];
    float4 o1; o1.x=o[4]; o1.y=o[5]; o1.z=o[6]; o1.w=o[7];
    *(float4*)po = o0;
    *(float4*)(po + 4) = o1;
    if (dg == 0) {
        float* pm = part_ml + ((size_t)bh * NCH + ch) * 32;
        pm[q] = M;
        pm[16 + q] = L;
    }
}

// ---------- combine partials -> oa bf16 (b,s,h*d) -------------------------------------
__global__ __launch_bounds__(256) void attn_comb_k(const float* __restrict__ part_o,
                                                   const float* __restrict__ part_ml,
                                                   u16* __restrict__ oa) {
    int bh = blockIdx.x, tid = threadIdx.x;
    __shared__ float sw[NCH][16], sLi[16];
    if (tid < 16) {
        float M = -1e30f;
        for (int c = 0; c < NCH; ++c) M = fmaxf(M, part_ml[((size_t)bh * NCH + c) * 32 + tid]);
        float L = 0.f;
        for (int c = 0; c < NCH; ++c) {
            const float* pm = part_ml + ((size_t)bh * NCH + c) * 32;
            float w = __expf(pm[tid] - M);
            sw[c][tid] = w;
            L += pm[16 + tid] * w;
        }
        sLi[tid] = 1.f / L;
    }
    __syncthreads();
    int q = tid >> 4, dg = tid & 15;
    float o[8];
#pragma unroll
    for (int j = 0; j < 8; ++j) o[j] = 0.f;
    for (int c = 0; c < NCH; ++c) {
        const float* po = part_o + ((size_t)bh * NCH + c) * (SS * DD) + q * DD + dg * 8;
        float4 a = *(const float4*)po;
        float4 b = *(const float4*)(po + 4);
        float w = sw[c][q];
        o[0]+=w*a.x; o[1]+=w*a.y; o[2]+=w*a.z; o[3]+=w*a.w;
        o[4]+=w*b.x; o[5]+=w*b.y; o[6]+=w*b.z; o[7]+=w*b.w;
    }
    float inv = sLi[q];
    int b = bh / HH, h = bh % HH;
    u16* yp = oa + (size_t)(b * SS + q) * HIDN + h * DD + dg * 8;
    s16x8 ov;
#pragma unroll
    for (int j = 0; j < 8; ++j) ov[j] = f2bfs(o[j] * inv);
    *(s16x8*)yp = ov;
}

// ---------- GEMM with residual: H[256][768] += A[256][K] @ Wt^T; optional split-K -----
template<int K, int KS>
__global__ __launch_bounds__(64) void gemm_res_k(const u16* __restrict__ A,
                                                 const u16* __restrict__ Wt,
                                                 float* __restrict__ H) {
    int lane = threadIdx.x, r = lane & 15, qg = lane >> 4;
    int n0 = blockIdx.x * 16, m0 = blockIdx.y * 16;
    const int KC = K / KS;
    int kbeg = blockIdx.z * KC;
    f32x4 acc = (f32x4){0.f, 0.f, 0.f, 0.f};
#pragma unroll 4
    for (int k0 = kbeg; k0 < kbeg + KC; k0 += 32) {
        s16x8 a  = *(const s16x8*)(A  + (size_t)(m0 + r) * K + k0 + qg * 8);
        s16x8 bw = *(const s16x8*)(Wt + (size_t)(n0 + r) * K + k0 + qg * 8);
        acc = __builtin_amdgcn_mfma_f32_16x16x32_bf16(a, bw, acc, 0, 0, 0);
    }
#pragma unroll
    for (int v = 0; v < 4; ++v) {
        size_t idx = (size_t)(m0 + qg * 4 + v) * HIDN + n0 + r;
        if (KS == 1) H[idx] += acc[v];
        else atomicAdd(&H[idx], acc[v]);
    }
}

// ---------- fused gate/up GEMM + SwiGLU -> fb bf16 [256][2048] -------------------------
__global__ __launch_bounds__(64) void gemm_gu_k(const u16* __restrict__ A,
                                                const u16* __restrict__ WgT,
                                                const u16* __restrict__ WuT,
                                                u16* __restrict__ F) {
    int lane = threadIdx.x, r = lane & 15, qg = lane >> 4;
    int n0 = blockIdx.x * 16, m0 = blockIdx.y * 16;
    f32x4 ag = (f32x4){0.f, 0.f, 0.f, 0.f};
    f32x4 au = (f32x4){0.f, 0.f, 0.f, 0.f};
#pragma unroll 2
    for (int k0 = 0; k0 < HIDN; k0 += 32) {
        s16x8 a  = *(const s16x8*)(A   + (size_t)(m0 + r) * HIDN + k0 + qg * 8);
        s16x8 bg = *(const s16x8*)(WgT + (size_t)(n0 + r) * HIDN + k0 + qg * 8);
        ag = __builtin_amdgcn_mfma_f32_16x16x32_bf16(a, bg, ag, 0, 0, 0);
        s16x8 bu = *(const s16x8*)(WuT + (size_t)(n0 + r) * HIDN + k0 + qg * 8);
        au = __builtin_amdgcn_mfma_f32_16x16x32_bf16(a, bu, au, 0, 0, 0);
    }
#pragma unroll
    for (int v = 0; v < 4; ++v) {
        float gv = ag[v], uv = au[v];
        float f = gv / (1.f + __expf(-gv)) * uv;
        F[(size_t)(m0 + qg * 4 + v) * FFN + n0 + r] = (u16)f2bfs(f);
    }
}

extern "C" void kernel_launch(void* const* d_in, const int* in_sizes, int n_in,
                              void* d_out, int out_size, void* d_ws, size_t ws_size,
                              hipStream_t stream) {
    (void)in_sizes; (void)n_in; (void)out_size; (void)ws_size;
    const float* emb     = (const float*)d_in[0];
    const float* k_cache = (const float*)d_in[4];
    const float* v_cache = (const float*)d_in[5];
    const float* Wq = (const float*)d_in[6];
    const float* bq = (const float*)d_in[7];
    const float* Wk = (const float*)d_in[8];
    const float* bk = (const float*)d_in[9];
    const float* Wv = (const float*)d_in[10];
    const float* bv = (const float*)d_in[11];
    const float* Wo = (const float*)d_in[12];
    const float* Wg = (const float*)d_in[13];
    const float* Wu = (const float*)d_in[14];
    const float* Wd = (const float*)d_in[15];
    const float* ln1 = (const float*)d_in[16];
    const float* ln2 = (const float*)d_in[17];
    const float* normf = (const float*)d_in[18];
    float* out = (float*)d_out;

    char* p = (char*)d_ws;
    auto alloc = [&](size_t bytes) { void* r = p; p += (bytes + 255) & ~255ull; return r; };
    const size_t WQKV = (size_t)HIDN * HH * DD;
    const size_t WMLP = (size_t)HIDN * FFN;
    u16* WqT = (u16*)alloc(LNUM * WQKV * 2);
    u16* WkT = (u16*)alloc(LNUM * WQKV * 2);
    u16* WvT = (u16*)alloc(LNUM * WQKV * 2);
    u16* WoT = (u16*)alloc(LNUM * WQKV * 2);
    u16* WgT = (u16*)alloc(LNUM * WMLP * 2);
    u16* WuT = (u16*)alloc(LNUM * WMLP * 2);
    u16* WdT = (u16*)alloc(LNUM * WMLP * 2);
    const int TOK = BB * SS;
    const size_t EMB_N = (size_t)TOK * HIDN;
    float* h  = (float*)alloc(EMB_N * 4);
    u16* hn   = (u16*)alloc(EMB_N * 2);
    u16* qr   = (u16*)alloc((size_t)BB * HH * SS * DD * 2);
    u16* kr   = (u16*)alloc((size_t)BB * HH * SS * DD * 2);
    u16* vr   = (u16*)alloc((size_t)BB * HH * SS * DD * 2);
    u16* oa   = (u16*)alloc(EMB_N * 2);
    u16* fb   = (u16*)alloc((size_t)TOK * FFN * 2);
    float* po  = (float*)alloc((size_t)96 * NCH * SS * DD * 4);
    float* pml = (float*)alloc((size_t)96 * NCH * 32 * 4);
    float2* tab = (float2*)alloc(16 * 64 * sizeof(float2));

    rope_tab_k<<<16, 64, 0, stream>>>(tab);
    wtrans_all_k<<<dim3(1728, LNUM), 256, 0, stream>>>(Wq, Wk, Wv, Wo, Wg, Wu, Wd,
                                                       WqT, WkT, WvT, WoT, WgT, WuT, WdT);
    hipMemcpyAsync(h, emb, EMB_N * sizeof(float), hipMemcpyDeviceToDevice, stream);

    const size_t KVOFF = (size_t)BB * HH * KVC * DD;
    for (int l = 0; l < LNUM; ++l) {
        rmsnorm_k<1><<<TOK, 64, 0, stream>>>(h, ln1 + l * HIDN, hn);
        qkv_k<<<dim3(3 * HH, BB), 64, 0, stream>>>(hn,
            WqT + l * WQKV, WkT + l * WQKV, WvT + l * WQKV,
            bq + l * HH * DD, bk + l * HH * DD, bv + l * HH * DD, tab, qr, kr, vr);
        // INSTRUMENTATION: attn_part launched 3x (idempotent). dur_us delta / 8 = t_att/layer.
        for (int rep = 0; rep < 3; ++rep)
            attn_part_k<<<dim3(BB * HH, NCH), 256, 0, stream>>>(qr, kr, vr,
                k_cache + (size_t)l * KVOFF, v_cache + (size_t)l * KVOFF, po, pml);
        attn_comb_k<<<BB * HH, 256, 0, stream>>>(po, pml, oa);
        gemm_res_k<HH * DD, 1><<<dim3(48, 16, 1), 64, 0, stream>>>(oa, WoT + l * WQKV, h);
        rmsnorm_k<1><<<TOK, 64, 0, stream>>>(h, ln2 + l * HIDN, hn);
        gemm_gu_k<<<dim3(128, 16), 64, 0, stream>>>(hn, WgT + l * WMLP, WuT + l * WMLP, fb);
        gemm_res_k<FFN, 4><<<dim3(48, 16, 4), 64, 0, stream>>>(fb, WdT + l * WMLP, h);
    }
    rmsnorm_k<0><<<TOK, 64, 0, stream>>>(h, normf, out);
}

// Round 7
// 438.718 us; speedup vs baseline: 1.7423x; 1.7423x over previous
//
#include <hip/hip_runtime.h>
#include <hip/hip_bf16.h>

#define LNUM 4
#define BB 16
#define SS 16
#define KVC 2048
#define HH 6
#define DD 128
#define HIDN 768
#define FFN 2048
#define NCH 17           // 16 cache chunks of 128 keys + 1 "new keys" chunk
#define ATT_SCALE 0.08838834764831845f
#define VT_PAD 136
#define OSH_PAD 132
#define AP 776           // u16 stride for [16][768] LDS (1552B = 97*16, 4 mod 32 dw)
#define AP3 1032         // u16 stride for [16][1024] LDS (2064B = 129*16, 4 mod 32 dw)

typedef unsigned short u16;
typedef short s16x8 __attribute__((ext_vector_type(8)));
typedef unsigned short u16x4 __attribute__((ext_vector_type(4)));
typedef float f32x4 __attribute__((ext_vector_type(4)));

__device__ __forceinline__ short f2bfs(float f) {
    __hip_bfloat16 h = __float2bfloat16(f);   // RNE; pairs into v_cvt_pk_bf16_f32
    return *reinterpret_cast<short*>(&h);
}

// ---------- rope table: tab[s][d] = (sin, cos) for pos=KVC+s ---------------------------
__global__ __launch_bounds__(64) void rope_tab_k(float2* __restrict__ tab) {
    int i = blockIdx.x * 64 + threadIdx.x;   // 1024
    int s = i >> 6, d = i & 63;
    float ts = powf(10000.f, (float)d * (1.f / 64.f));
    float rad = (float)(KVC + s) / ts;
    tab[i] = make_float2(sinf(rad), cosf(rad));
}

// ---------- ALL weight transposes in one launch ---------------------------------------
__global__ __launch_bounds__(256) void wtrans_all_k(
    const float* __restrict__ Wq, const float* __restrict__ Wk, const float* __restrict__ Wv,
    const float* __restrict__ Wo, const float* __restrict__ Wg, const float* __restrict__ Wu,
    const float* __restrict__ Wd,
    u16* __restrict__ WqT, u16* __restrict__ WkT, u16* __restrict__ WvT, u16* __restrict__ WoT,
    u16* __restrict__ WgT, u16* __restrict__ WuT, u16* __restrict__ WdT) {
    int idx = blockIdx.x, z = blockIdx.y;
    const float* in; u16* out; int K, N, nx, tt;
    if (idx < 432)      { tt = idx % 144; K = 768;  N = 768;  nx = 12;
                          int w = idx / 144;
                          in = (w==0)?Wq:(w==1)?Wk:Wv; out = (w==0)?WqT:(w==1)?WkT:WvT; }
    else if (idx < 576) { tt = idx - 432; K = 768;  N = 768;  nx = 12; in = Wo; out = WoT; }
    else if (idx < 1344){ tt = (idx - 576) % 384; K = 768; N = 2048; nx = 32;
                          in = (idx < 960) ? Wg : Wu; out = (idx < 960) ? WgT : WuT; }
    else                { tt = idx - 1344; K = 2048; N = 768; nx = 12; in = Wd; out = WdT; }
    int n0 = (tt % nx) * 64, k0 = (tt / nx) * 64;
    in  += (size_t)z * K * N;
    out += (size_t)z * K * N;
    __shared__ u16 T[64][65];
    int t = threadIdx.x;
#pragma unroll
    for (int i = 0; i < 16; ++i) {
        int f = i * 256 + t;
        int k = f >> 6, n = f & 63;
        T[k][n] = (u16)f2bfs(in[(size_t)(k0 + k) * N + n0 + n]);
    }
    __syncthreads();
#pragma unroll
    for (int i = 0; i < 2; ++i) {
        int f = i * 256 + t;
        int n = f >> 3, kg = f & 7;
        s16x8 v;
#pragma unroll
        for (int j = 0; j < 8; ++j) v[j] = (short)T[kg * 8 + j][n];
        *(s16x8*)(out + (size_t)(n0 + n) * K + k0 + kg * 8) = v;
    }
}

// ---------- final RMSNorm (f32 out) ---------------------------------------------------
__global__ __launch_bounds__(64) void rmsnorm_f_k(const float* __restrict__ x,
                                                  const float* __restrict__ w,
                                                  float* __restrict__ y) {
    int row = blockIdx.x, lane = threadIdx.x;
    const float* xp = x + (size_t)row * HIDN + lane * 12;
    float4 a = *(const float4*)xp;
    float4 b = *(const float4*)(xp + 4);
    float4 c = *(const float4*)(xp + 8);
    float s = a.x*a.x + a.y*a.y + a.z*a.z + a.w*a.w
            + b.x*b.x + b.y*b.y + b.z*b.z + b.w*b.w
            + c.x*c.x + c.y*c.y + c.z*c.z + c.w*c.w;
    for (int m = 1; m < 64; m <<= 1) s += __shfl_xor(s, m);
    float rq = rsqrtf(s * (1.f / 768.f) + 1e-6f);
    const float* wp = w + lane * 12;
    float* yp = y + (size_t)row * HIDN + lane * 12;
#pragma unroll
    for (int i = 0; i < 3; ++i) {
        float4 xv = (i == 0) ? a : (i == 1) ? b : c;
        float4 o;
        o.x = xv.x*rq*wp[i*4]; o.y = xv.y*rq*wp[i*4+1];
        o.z = xv.z*rq*wp[i*4+2]; o.w = xv.w*rq*wp[i*4+3];
        *(float4*)(yp + i * 4) = o;
    }
}

// ---------- fused rmsnorm1 + QKV GEMM + bias + rope; WG = 4 waves ---------------------
// grid (18,16): x = kind*6+h, y = b. Wave w owns n-tiles {w, w+4} = cols d1=[16w,16w+16),
// d2 = d1+64 -> rope pairs stay within the wave.
__global__ __launch_bounds__(256) void qkv_k(const float* __restrict__ h,
                                             const float* __restrict__ ln1w,
                                             const u16* __restrict__ WqT, const u16* __restrict__ WkT,
                                             const u16* __restrict__ WvT,
                                             const float* __restrict__ bq, const float* __restrict__ bk,
                                             const float* __restrict__ bv,
                                             const float2* __restrict__ tab,
                                             u16* __restrict__ qr, u16* __restrict__ kr,
                                             u16* __restrict__ vr) {
    int x = blockIdx.x, b = blockIdx.y;
    int kind = x / HH, hh = x % HH;
    const u16* Wt = (kind == 0) ? WqT : (kind == 1) ? WkT : WvT;
    const float* bias = (kind == 0) ? bq : (kind == 1) ? bk : bv;
    u16* outp = (kind == 0) ? qr : (kind == 1) ? kr : vr;
    int tid = threadIdx.x, wid = tid >> 6, lane = tid & 63, r = lane & 15, qg = lane >> 4;
    __shared__ u16 A[16][AP];
    float wln[12];
#pragma unroll
    for (int i = 0; i < 12; ++i) wln[i] = ln1w[lane * 12 + i];
    // norm: wave wid handles rows 4*wid .. 4*wid+3
#pragma unroll
    for (int i = 0; i < 4; ++i) {
        int row = wid * 4 + i;
        const float* xp = h + (size_t)(b * 16 + row) * HIDN + lane * 12;
        float4 a = *(const float4*)xp;
        float4 bb = *(const float4*)(xp + 4);
        float4 c = *(const float4*)(xp + 8);
        float s = a.x*a.x + a.y*a.y + a.z*a.z + a.w*a.w
                + bb.x*bb.x + bb.y*bb.y + bb.z*bb.z + bb.w*bb.w
                + c.x*c.x + c.y*c.y + c.z*c.z + c.w*c.w;
        for (int m = 1; m < 64; m <<= 1) s += __shfl_xor(s, m);
        float rq = rsqrtf(s * (1.f / 768.f) + 1e-6f);
#pragma unroll
        for (int j = 0; j < 3; ++j) {
            float4 xv = (j == 0) ? a : (j == 1) ? bb : c;
            u16x4 o;
#pragma unroll
            for (int t = 0; t < 4; ++t) o[t] = (u16)f2bfs((&xv.x)[t] * rq * wln[j * 4 + t]);
            *(u16x4*)(&A[row][lane * 12 + j * 4]) = o;
        }
    }
    __syncthreads();
    f32x4 acc0 = (f32x4){0.f,0.f,0.f,0.f};
    f32x4 acc1 = (f32x4){0.f,0.f,0.f,0.f};
    int d1 = wid * 16 + r, d2 = d1 + 64;
#pragma unroll 4
    for (int k0 = 0; k0 < HIDN; k0 += 32) {
        s16x8 a = *(const s16x8*)(&A[r][k0 + qg * 8]);
        s16x8 b0 = *(const s16x8*)(Wt + (size_t)(hh * DD + d1 - r + r) * HIDN + k0 + qg * 8);
        acc0 = __builtin_amdgcn_mfma_f32_16x16x32_bf16(a, b0, acc0, 0, 0, 0);
        s16x8 b1 = *(const s16x8*)(Wt + (size_t)(hh * DD + d2) * HIDN + k0 + qg * 8);
        acc1 = __builtin_amdgcn_mfma_f32_16x16x32_bf16(a, b1, acc1, 0, 0, 0);
    }
    int bh = b * HH + hh;
    float b1v = bias[hh * DD + d1], b2v = bias[hh * DD + d2];
    if (kind < 2) {
#pragma unroll
        for (int v = 0; v < 4; ++v) {
            int s = qg * 4 + v;
            float2 sc = tab[s * 64 + d1];
            float x1 = acc0[v] + b1v;
            float x2 = acc1[v] + b2v;
            outp[(size_t)(bh * 16 + s) * DD + d1] = (u16)f2bfs(x1 * sc.y - x2 * sc.x);
            outp[(size_t)(bh * 16 + s) * DD + d2] = (u16)f2bfs(x2 * sc.y + x1 * sc.x);
        }
    } else {
#pragma unroll
        for (int v = 0; v < 4; ++v) {
            int s = qg * 4 + v;
            outp[(size_t)(bh * 16 + s) * DD + d1] = (u16)f2bfs(acc0[v] + b1v);
            outp[(size_t)(bh * 16 + s) * DD + d2] = (u16)f2bfs(acc1[v] + b2v);
        }
    }
}

// ---------- attention partials: WG = 4 waves, 128 keys/WG (unchanged, at HBM floor) ---
__global__ __launch_bounds__(256) void attn_part_k(
    const u16* __restrict__ qr, const u16* __restrict__ kr, const u16* __restrict__ vr,
    const float* __restrict__ kc, const float* __restrict__ vc,
    float* __restrict__ part_o, float* __restrict__ part_ml) {
    int bh = blockIdx.x, ch = blockIdx.y;
    int tid = threadIdx.x, wid = tid >> 6, lane = tid & 63, r = lane & 15, qg = lane >> 4;
    bool isnew = (ch == NCH - 1);
    bool active = !isnew || (wid == 0);
    __shared__ __align__(16) char smem[128 * VT_PAD * 2];
    u16* Vt = (u16*)smem;
    float* Osh = (float*)smem;
    __shared__ __align__(16) u16 Plds[4][512];
    __shared__ float mlsh[4][32];

    const float* vbase_wg = vc + ((size_t)bh * KVC + ch * 128) * DD;
    const u16* vrn = vr + (size_t)bh * SS * DD;

    if (!isnew) {
#pragma unroll
        for (int i = 0; i < 8; ++i) {
            int flat = i * 256 + tid;
            int c4 = flat & 31, rp = flat >> 5;
            const float* p0 = vbase_wg + (size_t)(2 * rp) * DD + c4 * 4;
            float4 a = *(const float4*)p0;
            float4 b = *(const float4*)(p0 + DD);
#pragma unroll
            for (int c = 0; c < 4; ++c) {
                unsigned lo = (unsigned)(u16)f2bfs((&a.x)[c]);
                unsigned hi = (unsigned)(u16)f2bfs((&b.x)[c]);
                *(unsigned*)(Vt + (size_t)(c4 * 4 + c) * VT_PAD + 2 * rp) = lo | (hi << 16);
            }
        }
    } else {
#pragma unroll
        for (int i = 0; i < 16; ++i) {
            int flat = i * 256 + tid;
            int key = flat >> 7, d = flat & 127;
            u16 v = (key < SS) ? vrn[(size_t)key * DD + d] : (u16)0;
            Vt[(size_t)d * VT_PAD + key] = v;
        }
    }
    __syncthreads();

    float mrow[4] = {-1e30f, -1e30f, -1e30f, -1e30f};
    float lrow[4] = {0.f, 0.f, 0.f, 0.f};
    f32x4 oacc[8];
#pragma unroll
    for (int nt = 0; nt < 8; ++nt) oacc[nt] = (f32x4){0.f, 0.f, 0.f, 0.f};

    if (active) {
        s16x8 aq[4];
#pragma unroll
        for (int kk = 0; kk < 4; ++kk)
            aq[kk] = *(const s16x8*)(qr + (size_t)(bh * 16 + r) * DD + kk * 32 + qg * 8);
        const float* kbase = kc + ((size_t)bh * KVC + ch * 128 + wid * 32) * DD;
        const u16* krn = kr + (size_t)bh * SS * DD;

        f32x4 st[2];
        st[0] = (f32x4){0.f,0.f,0.f,0.f};
        st[1] = (f32x4){0.f,0.f,0.f,0.f};
#pragma unroll
        for (int t = 0; t < 2; ++t) {
            if (isnew && t == 1) continue;
#pragma unroll
            for (int kk = 0; kk < 4; ++kk) {
                s16x8 bk;
                if (isnew) {
                    bk = *(const s16x8*)(krn + (size_t)(t * 16 + r) * DD + kk * 32 + qg * 8);
                } else {
                    const float* p = kbase + (size_t)(t * 16 + r) * DD + kk * 32 + qg * 8;
                    float4 xx = *(const float4*)p;
                    float4 yy = *(const float4*)(p + 4);
                    bk[0]=f2bfs(xx.x); bk[1]=f2bfs(xx.y); bk[2]=f2bfs(xx.z); bk[3]=f2bfs(xx.w);
                    bk[4]=f2bfs(yy.x); bk[5]=f2bfs(yy.y); bk[6]=f2bfs(yy.z); bk[7]=f2bfs(yy.w);
                }
                st[t] = __builtin_amdgcn_mfma_f32_16x16x32_bf16(aq[kk], bk, st[t], 0, 0, 0);
            }
        }
#pragma unroll
        for (int t = 0; t < 2; ++t)
#pragma unroll
            for (int v = 0; v < 4; ++v) st[t][v] *= ATT_SCALE;
        if (isnew) {
#pragma unroll
            for (int v = 0; v < 4; ++v) {
                if (r > qg * 4 + v) st[0][v] = -1e9f;
                st[1][v] = -1e9f;
            }
        }
#pragma unroll
        for (int v = 0; v < 4; ++v) {
            float xm = fmaxf(st[0][v], st[1][v]);
            for (int msk = 1; msk < 16; msk <<= 1) xm = fmaxf(xm, __shfl_xor(xm, msk));
            mrow[v] = xm;
        }
#pragma unroll
        for (int t = 0; t < 2; ++t)
#pragma unroll
            for (int v = 0; v < 4; ++v) st[t][v] = __expf(st[t][v] - mrow[v]);
#pragma unroll
        for (int v = 0; v < 4; ++v) {
            float ss = st[0][v] + st[1][v];
            for (int msk = 1; msk < 16; msk <<= 1) ss += __shfl_xor(ss, msk);
            lrow[v] = ss;
        }
#pragma unroll
        for (int t = 0; t < 2; ++t)
#pragma unroll
            for (int v = 0; v < 4; ++v)
                Plds[wid][(qg * 4 + v) * 32 + t * 16 + r] = (u16)f2bfs(st[t][v]);
        s16x8 ap = *(const s16x8*)(&Plds[wid][r * 32 + qg * 8]);
#pragma unroll
        for (int nt = 0; nt < 8; ++nt) {
            s16x8 bv = *(const s16x8*)(Vt + (size_t)(nt * 16 + r) * VT_PAD + wid * 32 + qg * 8);
            oacc[nt] = __builtin_amdgcn_mfma_f32_16x16x32_bf16(ap, bv, oacc[nt], 0, 0, 0);
        }
    }
    __syncthreads();
#pragma unroll
    for (int nt = 0; nt < 8; ++nt)
#pragma unroll
        for (int v = 0; v < 4; ++v)
            Osh[(size_t)(wid * 16 + qg * 4 + v) * OSH_PAD + nt * 16 + r] = oacc[nt][v];
    if (r == 0) {
#pragma unroll
        for (int v = 0; v < 4; ++v) {
            mlsh[wid][qg * 4 + v] = mrow[v];
            mlsh[wid][16 + qg * 4 + v] = lrow[v];
        }
    }
    __syncthreads();
    int q = tid >> 4, dg = tid & 15;
    float M = -1e30f;
#pragma unroll
    for (int w = 0; w < 4; ++w) M = fmaxf(M, mlsh[w][q]);
    float L = 0.f, wgt[4];
#pragma unroll
    for (int w = 0; w < 4; ++w) {
        wgt[w] = __expf(mlsh[w][q] - M);
        L += mlsh[w][16 + q] * wgt[w];
    }
    float o[8];
#pragma unroll
    for (int j = 0; j < 8; ++j) o[j] = 0.f;
#pragma unroll
    for (int w = 0; w < 4; ++w) {
        const float* op = Osh + (size_t)(w * 16 + q) * OSH_PAD + dg * 8;
        float4 a = *(const float4*)op;
        float4 b = *(const float4*)(op + 4);
        o[0]+=wgt[w]*a.x; o[1]+=wgt[w]*a.y; o[2]+=wgt[w]*a.z; o[3]+=wgt[w]*a.w;
        o[4]+=wgt[w]*b.x; o[5]+=wgt[w]*b.y; o[6]+=wgt[w]*b.z; o[7]+=wgt[w]*b.w;
    }
    float* po = part_o + ((size_t)bh * NCH + ch) * (SS * DD) + q * DD + dg * 8;
    float4 o0; o0.x=o[0]; o0.y=o[1]; o0.z=o[2]; o0.w=o[3];
    float4 o1; o1.x=o[4]; o1.y=o[5]; o1.z=o[6]; o1.w=o[7];
    *(float4*)po = o0;
    *(float4*)(po + 4) = o1;
    if (dg == 0) {
        float* pm = part_ml + ((size_t)bh * NCH + ch) * 32;
        pm[q] = M;
        pm[16 + q] = L;
    }
}

// ---------- combine partials -> oa bf16 (b,s,h*d) -------------------------------------
__global__ __launch_bounds__(256) void attn_comb_k(const float* __restrict__ part_o,
                                                   const float* __restrict__ part_ml,
                                                   u16* __restrict__ oa) {
    int bh = blockIdx.x, tid = threadIdx.x;
    __shared__ float sw[NCH][16], sLi[16];
    if (tid < 16) {
        float M = -1e30f;
        for (int c = 0; c < NCH; ++c) M = fmaxf(M, part_ml[((size_t)bh * NCH + c) * 32 + tid]);
        float L = 0.f;
        for (int c = 0; c < NCH; ++c) {
            const float* pm = part_ml + ((size_t)bh * NCH + c) * 32;
            float w = __expf(pm[tid] - M);
            sw[c][tid] = w;
            L += pm[16 + tid] * w;
        }
        sLi[tid] = 1.f / L;
    }
    __syncthreads();
    int q = tid >> 4, dg = tid & 15;
    float o[8];
#pragma unroll
    for (int j = 0; j < 8; ++j) o[j] = 0.f;
    for (int c = 0; c < NCH; ++c) {
        const float* po = part_o + ((size_t)bh * NCH + c) * (SS * DD) + q * DD + dg * 8;
        float4 a = *(const float4*)po;
        float4 b = *(const float4*)(po + 4);
        float w = sw[c][q];
        o[0]+=w*a.x; o[1]+=w*a.y; o[2]+=w*a.z; o[3]+=w*a.w;
        o[4]+=w*b.x; o[5]+=w*b.y; o[6]+=w*b.z; o[7]+=w*b.w;
    }
    float inv = sLi[q];
    int b = bh / HH, h = bh % HH;
    u16* yp = oa + (size_t)(b * SS + q) * HIDN + h * DD + dg * 8;
    s16x8 ov;
#pragma unroll
    for (int j = 0; j < 8; ++j) ov[j] = f2bfs(o[j] * inv);
    *(s16x8*)yp = ov;
}

// ---------- Wo GEMM + residual, A staged in LDS; WG = 4 waves, grid (12,16) -----------
__global__ __launch_bounds__(256) void wo_res_k(const u16* __restrict__ oa,
                                                const u16* __restrict__ WoT,
                                                float* __restrict__ h) {
    int tid = threadIdx.x, wid = tid >> 6, lane = tid & 63, r = lane & 15, qg = lane >> 4;
    int b = blockIdx.y;
    __shared__ u16 A[16][AP];
#pragma unroll
    for (int i = 0; i < 6; ++i) {
        int idx8 = i * 256 + tid;            // 1536 vec8 = 16*768/8
        int row = idx8 / 96, c8 = idx8 % 96;
        *(s16x8*)(&A[row][c8 * 8]) =
            *(const s16x8*)(oa + (size_t)(b * 16 + row) * HIDN + c8 * 8);
    }
    __syncthreads();
    int n0 = blockIdx.x * 64 + wid * 16;
    f32x4 acc = (f32x4){0.f, 0.f, 0.f, 0.f};
#pragma unroll 4
    for (int k0 = 0; k0 < HIDN; k0 += 32) {
        s16x8 a  = *(const s16x8*)(&A[r][k0 + qg * 8]);
        s16x8 bw = *(const s16x8*)(WoT + (size_t)(n0 + r) * HIDN + k0 + qg * 8);
        acc = __builtin_amdgcn_mfma_f32_16x16x32_bf16(a, bw, acc, 0, 0, 0);
    }
#pragma unroll
    for (int v = 0; v < 4; ++v)
        h[(size_t)(b * 16 + qg * 4 + v) * HIDN + n0 + r] += acc[v];
}

// ---------- fused rmsnorm2 + gate/up GEMM + SwiGLU; WG = 4 waves, grid (32,16) --------
__global__ __launch_bounds__(256) void ln2gu_k(const float* __restrict__ h,
                                               const float* __restrict__ ln2w,
                                               const u16* __restrict__ WgT,
                                               const u16* __restrict__ WuT,
                                               u16* __restrict__ F) {
    int tid = threadIdx.x, wid = tid >> 6, lane = tid & 63, r = lane & 15, qg = lane >> 4;
    int m0 = blockIdx.y * 16;
    __shared__ u16 A[16][AP];
    float wln[12];
#pragma unroll
    for (int i = 0; i < 12; ++i) wln[i] = ln2w[lane * 12 + i];
#pragma unroll
    for (int i = 0; i < 4; ++i) {
        int row = wid * 4 + i;
        const float* xp = h + (size_t)(m0 + row) * HIDN + lane * 12;
        float4 a = *(const float4*)xp;
        float4 bb = *(const float4*)(xp + 4);
        float4 c = *(const float4*)(xp + 8);
        float s = a.x*a.x + a.y*a.y + a.z*a.z + a.w*a.w
                + bb.x*bb.x + bb.y*bb.y + bb.z*bb.z + bb.w*bb.w
                + c.x*c.x + c.y*c.y + c.z*c.z + c.w*c.w;
        for (int m = 1; m < 64; m <<= 1) s += __shfl_xor(s, m);
        float rq = rsqrtf(s * (1.f / 768.f) + 1e-6f);
#pragma unroll
        for (int j = 0; j < 3; ++j) {
            float4 xv = (j == 0) ? a : (j == 1) ? bb : c;
            u16x4 o;
#pragma unroll
            for (int t = 0; t < 4; ++t) o[t] = (u16)f2bfs((&xv.x)[t] * rq * wln[j * 4 + t]);
            *(u16x4*)(&A[row][lane * 12 + j * 4]) = o;
        }
    }
    __syncthreads();
    int n0 = blockIdx.x * 64 + wid * 16;
    f32x4 ag = (f32x4){0.f, 0.f, 0.f, 0.f};
    f32x4 au = (f32x4){0.f, 0.f, 0.f, 0.f};
#pragma unroll 4
    for (int k0 = 0; k0 < HIDN; k0 += 32) {
        s16x8 a  = *(const s16x8*)(&A[r][k0 + qg * 8]);
        s16x8 bg = *(const s16x8*)(WgT + (size_t)(n0 + r) * HIDN + k0 + qg * 8);
        ag = __builtin_amdgcn_mfma_f32_16x16x32_bf16(a, bg, ag, 0, 0, 0);
        s16x8 bu = *(const s16x8*)(WuT + (size_t)(n0 + r) * HIDN + k0 + qg * 8);
        au = __builtin_amdgcn_mfma_f32_16x16x32_bf16(a, bu, au, 0, 0, 0);
    }
#pragma unroll
    for (int v = 0; v < 4; ++v) {
        float gv = ag[v], uv = au[v];
        float f = gv / (1.f + __expf(-gv)) * uv;
        F[(size_t)(m0 + qg * 4 + v) * FFN + n0 + r] = (u16)f2bfs(f);
    }
}

// ---------- down GEMM + residual (split-K=2, atomics), A staged; grid (12,16,2) -------
__global__ __launch_bounds__(256) void down_res_k(const u16* __restrict__ F,
                                                  const u16* __restrict__ WdT,
                                                  float* __restrict__ H) {
    int tid = threadIdx.x, wid = tid >> 6, lane = tid & 63, r = lane & 15, qg = lane >> 4;
    int m0 = blockIdx.y * 16;
    int kbeg = blockIdx.z * 1024;
    __shared__ u16 A[16][AP3];
#pragma unroll
    for (int i = 0; i < 8; ++i) {
        int idx8 = i * 256 + tid;            // 2048 vec8 = 16*1024/8
        int row = idx8 >> 7, c8 = idx8 & 127;
        *(s16x8*)(&A[row][c8 * 8]) =
            *(const s16x8*)(F + (size_t)(m0 + row) * FFN + kbeg + c8 * 8);
    }
    __syncthreads();
    int n0 = blockIdx.x * 64 + wid * 16;
    f32x4 acc = (f32x4){0.f, 0.f, 0.f, 0.f};
#pragma unroll 4
    for (int k0 = 0; k0 < 1024; k0 += 32) {
        s16x8 a  = *(const s16x8*)(&A[r][k0 + qg * 8]);
        s16x8 bw = *(const s16x8*)(WdT + (size_t)(n0 + r) * FFN + kbeg + k0 + qg * 8);
        acc = __builtin_amdgcn_mfma_f32_16x16x32_bf16(a, bw, acc, 0, 0, 0);
    }
#pragma unroll
    for (int v = 0; v < 4; ++v)
        atomicAdd(&H[(size_t)(m0 + qg * 4 + v) * HIDN + n0 + r], acc[v]);
}

extern "C" void kernel_launch(void* const* d_in, const int* in_sizes, int n_in,
                              void* d_out, int out_size, void* d_ws, size_t ws_size,
                              hipStream_t stream) {
    (void)in_sizes; (void)n_in; (void)out_size; (void)ws_size;
    const float* emb     = (const float*)d_in[0];
    const float* k_cache = (const float*)d_in[4];
    const float* v_cache = (const float*)d_in[5];
    const float* Wq = (const float*)d_in[6];
    const float* bq = (const float*)d_in[7];
    const float* Wk = (const float*)d_in[8];
    const float* bk = (const float*)d_in[9];
    const float* Wv = (const float*)d_in[10];
    const float* bv = (const float*)d_in[11];
    const float* Wo = (const float*)d_in[12];
    const float* Wg = (const float*)d_in[13];
    const float* Wu = (const float*)d_in[14];
    const float* Wd = (const float*)d_in[15];
    const float* ln1 = (const float*)d_in[16];
    const float* ln2 = (const float*)d_in[17];
    const float* normf = (const float*)d_in[18];
    float* out = (float*)d_out;

    char* p = (char*)d_ws;
    auto alloc = [&](size_t bytes) { void* r = p; p += (bytes + 255) & ~255ull; return r; };
    const size_t WQKV = (size_t)HIDN * HH * DD;
    const size_t WMLP = (size_t)HIDN * FFN;
    u16* WqT = (u16*)alloc(LNUM * WQKV * 2);
    u16* WkT = (u16*)alloc(LNUM * WQKV * 2);
    u16* WvT = (u16*)alloc(LNUM * WQKV * 2);
    u16* WoT = (u16*)alloc(LNUM * WQKV * 2);
    u16* WgT = (u16*)alloc(LNUM * WMLP * 2);
    u16* WuT = (u16*)alloc(LNUM * WMLP * 2);
    u16* WdT = (u16*)alloc(LNUM * WMLP * 2);
    const int TOK = BB * SS;
    const size_t EMB_N = (size_t)TOK * HIDN;
    float* h  = (float*)alloc(EMB_N * 4);
    u16* qr   = (u16*)alloc((size_t)BB * HH * SS * DD * 2);
    u16* kr   = (u16*)alloc((size_t)BB * HH * SS * DD * 2);
    u16* vr   = (u16*)alloc((size_t)BB * HH * SS * DD * 2);
    u16* oa   = (u16*)alloc(EMB_N * 2);
    u16* fb   = (u16*)alloc((size_t)TOK * FFN * 2);
    float* po  = (float*)alloc((size_t)96 * NCH * SS * DD * 4);
    float* pml = (float*)alloc((size_t)96 * NCH * 32 * 4);
    float2* tab = (float2*)alloc(16 * 64 * sizeof(float2));

    rope_tab_k<<<16, 64, 0, stream>>>(tab);
    wtrans_all_k<<<dim3(1728, LNUM), 256, 0, stream>>>(Wq, Wk, Wv, Wo, Wg, Wu, Wd,
                                                       WqT, WkT, WvT, WoT, WgT, WuT, WdT);
    hipMemcpyAsync(h, emb, EMB_N * sizeof(float), hipMemcpyDeviceToDevice, stream);

    const size_t KVOFF = (size_t)BB * HH * KVC * DD;
    for (int l = 0; l < LNUM; ++l) {
        qkv_k<<<dim3(3 * HH, BB), 256, 0, stream>>>(h, ln1 + l * HIDN,
            WqT + l * WQKV, WkT + l * WQKV, WvT + l * WQKV,
            bq + l * HH * DD, bk + l * HH * DD, bv + l * HH * DD, tab, qr, kr, vr);
        attn_part_k<<<dim3(BB * HH, NCH), 256, 0, stream>>>(qr, kr, vr,
            k_cache + (size_t)l * KVOFF, v_cache + (size_t)l * KVOFF, po, pml);
        attn_comb_k<<<BB * HH, 256, 0, stream>>>(po, pml, oa);
        wo_res_k<<<dim3(12, BB), 256, 0, stream>>>(oa, WoT + l * WQKV, h);
        ln2gu_k<<<dim3(32, BB), 256, 0, stream>>>(h, ln2 + l * HIDN,
            WgT + l * WMLP, WuT + l * WMLP, fb);
        down_res_k<<<dim3(12, BB, 2), 256, 0, stream>>>(fb, WdT + l * WMLP, h);
    }
    rmsnorm_f_k<<<TOK, 64, 0, stream>>>(h, normf, out);
}